// Round 1
// baseline (1271.914 us; speedup 1.0000x reference)
//
#include <hip/hip_runtime.h>
#include <hip/hip_bf16.h>

#define NN 50000
#define NE 600000
#define DIM 128
#define NEG 0.2f
#define GEPS 1e-16f

__device__ __forceinline__ float leaky(float x) { return x > 0.f ? x : NEG * x; }

// ---------------- embed gather: h[n][:] = embed[x[n]][:] ----------------
__global__ __launch_bounds__(256) void k_gather(const int* __restrict__ x,
                                                const float* __restrict__ embed,
                                                float* __restrict__ h) {
  int i = blockIdx.x * blockDim.x + threadIdx.x;  // over NN*32 float4s
  if (i >= NN * 32) return;
  int n = i >> 5, c4 = i & 31;
  int v = x[n];
  ((float4*)h)[n * 32 + c4] = ((const float4*)embed)[v * 32 + c4];
}

// ---------------- CSR build ----------------
__global__ __launch_bounds__(256) void k_count(const int* __restrict__ dst,
                                               int* __restrict__ cnt) {
  int e = blockIdx.x * blockDim.x + threadIdx.x;
  if (e < NE) atomicAdd(&cnt[dst[e]], 1);
}

__global__ __launch_bounds__(1024) void k_scan(int* __restrict__ cnt_cur,
                                               int* __restrict__ roff) {
  __shared__ int part[1024];
  const int t = threadIdx.x;
  const int CH = (NN + 1023) / 1024;  // 49
  const int base = t * CH;
  int s = 0;
  for (int i = 0; i < CH; i++) {
    int idx = base + i;
    if (idx < NN) s += cnt_cur[idx];
  }
  part[t] = s;
  __syncthreads();
  for (int off = 1; off < 1024; off <<= 1) {
    int v = (t >= off) ? part[t - off] : 0;
    __syncthreads();
    part[t] += v;
    __syncthreads();
  }
  int run = (t == 0) ? 0 : part[t - 1];
  for (int i = 0; i < CH; i++) {
    int idx = base + i;
    if (idx < NN) {
      int c = cnt_cur[idx];
      roff[idx] = run;
      cnt_cur[idx] = run;  // becomes insertion cursor
      run += c;
    }
  }
  if (t == 1023) roff[NN] = part[1023];
}

__global__ __launch_bounds__(256) void k_fill(const int* __restrict__ src,
                                              const int* __restrict__ dst,
                                              int* __restrict__ cur,
                                              int* __restrict__ ssrc) {
  int e = blockIdx.x * blockDim.x + threadIdx.x;
  if (e < NE) {
    int p = atomicAdd(&cur[dst[e]], 1);
    ssrc[p] = src[e];
  }
}

// ---------------- linear: hlin = xin @ W, + attention dot products ----------------
// block = 256 threads, tile = 64 rows x 128 cols; thread: 4 rows x (2x float4 cols)
__global__ __launch_bounds__(256) void k_linear(const float* __restrict__ xin,
                                                const float* __restrict__ W,
                                                const float* __restrict__ a_src,
                                                const float* __restrict__ a_dst,
                                                float* __restrict__ hlin,
                                                float* __restrict__ asrc,
                                                float* __restrict__ adst) {
  __shared__ __align__(16) float w_lds[32 * 128];
  __shared__ __align__(16) float x_lds[64 * 36];
  __shared__ float red_s[256];
  __shared__ float red_d[256];
  const int t = threadIdx.x;
  const int tx = t & 15, ty = t >> 4;
  const int n0 = blockIdx.x * 64;

  float acc[4][8];
#pragma unroll
  for (int r = 0; r < 4; r++)
#pragma unroll
    for (int j = 0; j < 8; j++) acc[r][j] = 0.f;

  for (int kc = 0; kc < 128; kc += 32) {
#pragma unroll
    for (int i = 0; i < 4; i++) {
      int idx = i * 256 + t;  // 1024 float4 of W chunk
      int kr = idx >> 5, c4 = idx & 31;
      ((float4*)w_lds)[kr * 32 + c4] = ((const float4*)W)[(kc + kr) * 32 + c4];
    }
#pragma unroll
    for (int i = 0; i < 2; i++) {
      int idx = i * 256 + t;  // 512 float4 of x chunk
      int r = idx >> 3, k4 = idx & 7;
      int n = n0 + r;
      float4 v = make_float4(0.f, 0.f, 0.f, 0.f);
      if (n < NN) v = ((const float4*)xin)[n * 32 + (kc >> 2) + k4];
      *((float4*)&x_lds[r * 36 + k4 * 4]) = v;
    }
    __syncthreads();
#pragma unroll
    for (int kk = 0; kk < 32; kk += 4) {
      float4 xv[4];
#pragma unroll
      for (int rr = 0; rr < 4; rr++)
        xv[rr] = *((const float4*)&x_lds[(ty * 4 + rr) * 36 + kk]);
#pragma unroll
      for (int q = 0; q < 4; q++) {
        int k = kk + q;
        float4 w0 = ((const float4*)w_lds)[k * 32 + tx];
        float4 w1 = ((const float4*)w_lds)[k * 32 + 16 + tx];
#pragma unroll
        for (int rr = 0; rr < 4; rr++) {
          float xs = q == 0 ? xv[rr].x : q == 1 ? xv[rr].y : q == 2 ? xv[rr].z : xv[rr].w;
          acc[rr][0] += xs * w0.x;
          acc[rr][1] += xs * w0.y;
          acc[rr][2] += xs * w0.z;
          acc[rr][3] += xs * w0.w;
          acc[rr][4] += xs * w1.x;
          acc[rr][5] += xs * w1.y;
          acc[rr][6] += xs * w1.z;
          acc[rr][7] += xs * w1.w;
        }
      }
    }
    __syncthreads();
  }

  // epilogue: store hlin, reduce per-head attention dots in LDS
  red_s[t] = 0.f;
  red_d[t] = 0.f;
  __syncthreads();
  const int hA = tx >> 3, hB = 2 + (tx >> 3);
#pragma unroll
  for (int rr = 0; rr < 4; rr++) {
    int n = n0 + ty * 4 + rr;
    if (n < NN) {
      float4 o0 = make_float4(acc[rr][0], acc[rr][1], acc[rr][2], acc[rr][3]);
      float4 o1 = make_float4(acc[rr][4], acc[rr][5], acc[rr][6], acc[rr][7]);
      ((float4*)hlin)[n * 32 + tx] = o0;
      ((float4*)hlin)[n * 32 + 16 + tx] = o1;
      float sA = 0.f, sB = 0.f, dA = 0.f, dB = 0.f;
#pragma unroll
      for (int j = 0; j < 4; j++) {
        sA += acc[rr][j] * a_src[tx * 4 + j];
        dA += acc[rr][j] * a_dst[tx * 4 + j];
        sB += acc[rr][4 + j] * a_src[64 + tx * 4 + j];
        dB += acc[rr][4 + j] * a_dst[64 + tx * 4 + j];
      }
      int r = ty * 4 + rr;
      atomicAdd(&red_s[r * 4 + hA], sA);
      atomicAdd(&red_s[r * 4 + hB], sB);
      atomicAdd(&red_d[r * 4 + hA], dA);
      atomicAdd(&red_d[r * 4 + hB], dB);
    }
  }
  __syncthreads();
  {
    int r = t >> 2, hd = t & 3;
    int n = n0 + r;
    if (n < NN) {
      asrc[n * 4 + hd] = red_s[t];
      adst[n * 4 + hd] = red_d[t];
    }
  }
}

// ---------------- aggregate: one wave per destination node ----------------
__global__ __launch_bounds__(256) void k_aggregate(const float* __restrict__ hlin,
                                                   const float* __restrict__ asrcv,
                                                   const float* __restrict__ adstv,
                                                   const int* __restrict__ roff,
                                                   const int* __restrict__ ssrc,
                                                   const float* __restrict__ bias,
                                                   float* __restrict__ hout) {
  const int lane = threadIdx.x & 63;
  const int n = blockIdx.x * 4 + (threadIdx.x >> 6);
  if (n >= NN) return;
  const int beg = roff[n], end = roff[n + 1];
  const float4 ad = ((const float4*)adstv)[n];
  const float4 a_self = ((const float4*)asrcv)[n];

  float es0 = leaky(a_self.x + ad.x), es1 = leaky(a_self.y + ad.y);
  float es2 = leaky(a_self.z + ad.z), es3 = leaky(a_self.w + ad.w);
  float m0 = es0, m1 = es1, m2 = es2, m3 = es3;
  for (int i = beg + lane; i < end; i += 64) {
    int s = ssrc[i];
    float4 a = ((const float4*)asrcv)[s];
    m0 = fmaxf(m0, leaky(a.x + ad.x));
    m1 = fmaxf(m1, leaky(a.y + ad.y));
    m2 = fmaxf(m2, leaky(a.z + ad.z));
    m3 = fmaxf(m3, leaky(a.w + ad.w));
  }
#pragma unroll
  for (int off = 1; off < 64; off <<= 1) {
    m0 = fmaxf(m0, __shfl_xor(m0, off));
    m1 = fmaxf(m1, __shfl_xor(m1, off));
    m2 = fmaxf(m2, __shfl_xor(m2, off));
    m3 = fmaxf(m3, __shfl_xor(m3, off));
  }

  const int hh = lane >> 4;
  float2 hv = ((const float2*)hlin)[n * 64 + lane];
  float e0s = __expf(es0 - m0), e1s = __expf(es1 - m1);
  float e2s = __expf(es2 - m2), e3s = __expf(es3 - m3);
  float exsh = hh == 0 ? e0s : hh == 1 ? e1s : hh == 2 ? e2s : e3s;
  float acc0 = exsh * hv.x, acc1 = exsh * hv.y;
  float d0 = 0.f, d1 = 0.f, d2 = 0.f, d3 = 0.f;

  for (int base = beg; base < end; base += 64) {
    int myi = base + lane;
    int s = 0;
    float e0 = 0.f, e1 = 0.f, e2 = 0.f, e3 = 0.f;
    if (myi < end) {
      s = ssrc[myi];
      float4 a = ((const float4*)asrcv)[s];
      e0 = __expf(leaky(a.x + ad.x) - m0); d0 += e0;
      e1 = __expf(leaky(a.y + ad.y) - m1); d1 += e1;
      e2 = __expf(leaky(a.z + ad.z) - m2); d2 += e2;
      e3 = __expf(leaky(a.w + ad.w) - m3); d3 += e3;
    }
    int cnt = min(64, end - base);
    for (int j = 0; j < cnt; j++) {
      int sj = __shfl(s, j);
      float x0 = __shfl(e0, j), x1 = __shfl(e1, j);
      float x2 = __shfl(e2, j), x3 = __shfl(e3, j);
      float exj = hh == 0 ? x0 : hh == 1 ? x1 : hh == 2 ? x2 : x3;
      float2 hs = ((const float2*)hlin)[sj * 64 + lane];
      acc0 += exj * hs.x;
      acc1 += exj * hs.y;
    }
  }
#pragma unroll
  for (int off = 1; off < 64; off <<= 1) {
    d0 += __shfl_xor(d0, off);
    d1 += __shfl_xor(d1, off);
    d2 += __shfl_xor(d2, off);
    d3 += __shfl_xor(d3, off);
  }
  d0 += e0s; d1 += e1s; d2 += e2s; d3 += e3s;
  float dh = hh == 0 ? d0 : hh == 1 ? d1 : hh == 2 ? d2 : d3;
  float inv = 1.f / (dh + GEPS);
  int c0 = lane * 2;
  float o0 = fmaxf(acc0 * inv + bias[c0], 0.f);
  float o1 = fmaxf(acc1 * inv + bias[c0 + 1], 0.f);
  hout[n * DIM + c0] = o0;
  hout[n * DIM + c0 + 1] = o1;
}

// ---------------- global attention pooling (fused gate + weighted sum) ----------------
__global__ __launch_bounds__(256) void k_pool(const float* __restrict__ h,
                                              const float* __restrict__ gate_w,
                                              const float* __restrict__ gate_b,
                                              float* __restrict__ acc_out) {
  const int lane = threadIdx.x & 63;
  const int widg = blockIdx.x * 4 + (threadIdx.x >> 6);
  const int nw = gridDim.x * 4;
  const float w0 = gate_w[lane * 2], w1 = gate_w[lane * 2 + 1];
  const float gb = gate_b[0];
  float acc0 = 0.f, acc1 = 0.f, se = 0.f;
  for (int n = widg; n < NN; n += nw) {
    float2 hv = ((const float2*)h)[n * 64 + lane];
    float p = hv.x * w0 + hv.y * w1;
#pragma unroll
    for (int off = 1; off < 64; off <<= 1) p += __shfl_xor(p, off);
    float sg = 1.f / (1.f + __expf(-(p + gb)));
    float e = __expf(sg);
    se += e;
    acc0 += e * hv.x;
    acc1 += e * hv.y;
  }
  atomicAdd(&acc_out[lane * 2], acc0);
  atomicAdd(&acc_out[lane * 2 + 1], acc1);
  if (lane == 0) atomicAdd(&acc_out[128], se);
}

// ---------------- final MLP ----------------
__global__ __launch_bounds__(128) void k_mlp(const float* __restrict__ p1,
                                             const float* __restrict__ p2,
                                             const float* __restrict__ fc1_w,
                                             const float* __restrict__ fc1_b,
                                             const float* __restrict__ fc2_w,
                                             const float* __restrict__ fc2_b,
                                             float* __restrict__ out) {
  __shared__ float cat[256];
  __shared__ float red[2];
  const int t = threadIdx.x;
  cat[t] = p1[t] / p1[128];
  cat[128 + t] = p2[t] / p2[128];
  __syncthreads();
  float a = fc1_b[t];
  for (int k = 0; k < 256; k++) a += cat[k] * fc1_w[k * 128 + t];
  a = fmaxf(a, 0.f);
  float v = a * fc2_w[t];
#pragma unroll
  for (int off = 1; off < 64; off <<= 1) v += __shfl_xor(v, off);
  if ((t & 63) == 0) red[t >> 6] = v;
  __syncthreads();
  if (t == 0) out[0] = red[0] + red[1] + fc2_b[0];
}

extern "C" void kernel_launch(void* const* d_in, const int* in_sizes, int n_in,
                              void* d_out, int out_size, void* d_ws, size_t ws_size,
                              hipStream_t stream) {
  (void)in_sizes; (void)n_in; (void)out_size; (void)ws_size;
  const int* x1 = (const int*)d_in[0];
  const int* x2 = (const int*)d_in[1];
  const int* ei1 = (const int*)d_in[2];
  const int* ei2 = (const int*)d_in[3];
  const float* embed = (const float*)d_in[4];
  const float* W = (const float*)d_in[5];
  const float* attS = (const float*)d_in[6];
  const float* attD = (const float*)d_in[7];
  const float* bias = (const float*)d_in[8];
  const float* gw = (const float*)d_in[9];
  const float* gb = (const float*)d_in[10];
  const float* f1w = (const float*)d_in[11];
  const float* f1b = (const float*)d_in[12];
  const float* f2w = (const float*)d_in[13];
  const float* f2b = (const float*)d_in[14];
  float* out = (float*)d_out;

  char* ws = (char*)d_ws;
  size_t off = 0;
  auto alloc = [&](size_t bytes) {
    void* p = ws + off;
    off = (off + bytes + 255) & ~size_t(255);
    return p;
  };
  float* h_in = (float*)alloc(size_t(NN) * DIM * 4);
  float* h_lin = (float*)alloc(size_t(NN) * DIM * 4);
  float* asrc = (float*)alloc(size_t(NN) * 4 * 4);
  float* adst = (float*)alloc(size_t(NN) * 4 * 4);
  int* roff = (int*)alloc(size_t(NN + 1) * 4);
  int* cur = (int*)alloc(size_t(NN) * 4);
  int* ssrc = (int*)alloc(size_t(NE) * 4);
  float* pool = (float*)alloc(2 * 129 * 4);

  hipMemsetAsync(pool, 0, 2 * 129 * 4, stream);

  for (int g = 0; g < 2; ++g) {
    const int* xg = g ? x2 : x1;
    const int* eg = g ? ei2 : ei1;
    const int* esrc = eg;
    const int* edst = eg + NE;

    k_gather<<<(NN * 32 + 255) / 256, 256, 0, stream>>>(xg, embed, h_in);
    hipMemsetAsync(cur, 0, size_t(NN) * 4, stream);
    k_count<<<(NE + 255) / 256, 256, 0, stream>>>(edst, cur);
    k_scan<<<1, 1024, 0, stream>>>(cur, roff);
    k_fill<<<(NE + 255) / 256, 256, 0, stream>>>(esrc, edst, cur, ssrc);

    for (int l = 0; l < 3; ++l) {
      k_linear<<<(NN + 63) / 64, 256, 0, stream>>>(
          h_in, W + l * DIM * DIM, attS + l * DIM, attD + l * DIM, h_lin, asrc, adst);
      k_aggregate<<<(NN + 3) / 4, 256, 0, stream>>>(
          h_lin, asrc, adst, roff, ssrc, bias + l * DIM, h_in);
    }
    k_pool<<<128, 256, 0, stream>>>(h_in, gw, gb, pool + g * 129);
  }
  k_mlp<<<1, 128, 0, stream>>>(pool, pool + 129, f1w, f1b, f2w, f2b, out);
}

// Round 2
// 962.745 us; speedup vs baseline: 1.3211x; 1.3211x over previous
//
#include <hip/hip_runtime.h>
#include <hip/hip_bf16.h>

#define NN 50000
#define NE 600000
#define DIM 128
#define NEG 0.2f
#define GEPS 1e-16f

__device__ __forceinline__ float leaky(float x) { return x > 0.f ? x : NEG * x; }

// ---------------- embed gather: h[n][:] = embed[idx(n)][:] ----------------
__global__ __launch_bounds__(256) void k_gather(const int* __restrict__ xA,
                                                const int* __restrict__ xB,
                                                const float* __restrict__ embed,
                                                float* __restrict__ h, int ntot) {
  int i = blockIdx.x * blockDim.x + threadIdx.x;  // over ntot*32 float4s
  if (i >= ntot * 32) return;
  int n = i >> 5, c4 = i & 31;
  int v = (n < NN) ? xA[n] : xB[n - NN];
  ((float4*)h)[n * 32 + c4] = ((const float4*)embed)[v * 32 + c4];
}

// ---------------- CSR build ----------------
__global__ __launch_bounds__(256) void k_count(const int* __restrict__ d1,
                                               const int* __restrict__ d2,
                                               int* __restrict__ cnt, int netot) {
  int e = blockIdx.x * blockDim.x + threadIdx.x;
  if (e >= netot) return;
  int dst = (e < NE) ? d1[e] : d2[e - NE] + NN;
  atomicAdd(&cnt[dst], 1);
}

// multi-block scan: (1) block-local exclusive scan + block sums
__global__ __launch_bounds__(1024) void k_scan1(const int* __restrict__ cnt,
                                                int* __restrict__ roff,
                                                int* __restrict__ partials, int nn) {
  __shared__ int part[1024];
  const int t = threadIdx.x;
  const int idx = blockIdx.x * 1024 + t;
  int v = (idx < nn) ? cnt[idx] : 0;
  part[t] = v;
  __syncthreads();
  for (int off = 1; off < 1024; off <<= 1) {
    int x = (t >= off) ? part[t - off] : 0;
    __syncthreads();
    part[t] += x;
    __syncthreads();
  }
  if (idx < nn) roff[idx] = part[t] - v;
  if (t == 1023) partials[blockIdx.x] = part[1023];
}

// (2) scan of block sums (nb <= 128)
__global__ __launch_bounds__(128) void k_scan2(int* __restrict__ partials, int nb) {
  __shared__ int part[128];
  const int t = threadIdx.x;
  int v = (t < nb) ? partials[t] : 0;
  part[t] = v;
  __syncthreads();
  for (int off = 1; off < 128; off <<= 1) {
    int x = (t >= off) ? part[t - off] : 0;
    __syncthreads();
    part[t] += x;
    __syncthreads();
  }
  if (t < nb) partials[t] = part[t] - v;
}

// (3) add back block offsets, emit insertion cursors
__global__ __launch_bounds__(1024) void k_scan3(int* __restrict__ roff,
                                                int* __restrict__ cur,
                                                const int* __restrict__ partials,
                                                int nn, int netot) {
  int idx = blockIdx.x * 1024 + threadIdx.x;
  if (idx < nn) {
    int v = roff[idx] + partials[blockIdx.x];
    roff[idx] = v;
    cur[idx] = v;
  }
  if (idx == 0) roff[nn] = netot;
}

__global__ __launch_bounds__(256) void k_fill(const int* __restrict__ s1,
                                              const int* __restrict__ d1,
                                              const int* __restrict__ s2,
                                              const int* __restrict__ d2,
                                              int* __restrict__ cur,
                                              int* __restrict__ ssrc, int netot) {
  int e = blockIdx.x * blockDim.x + threadIdx.x;
  if (e >= netot) return;
  int s, d;
  if (e < NE) { s = s1[e]; d = d1[e]; }
  else        { s = s2[e - NE] + NN; d = d2[e - NE] + NN; }
  int p = atomicAdd(&cur[d], 1);
  ssrc[p] = s;
}

// ---------------- linear: hlin = xin @ W, + attention dot products ----------------
__global__ __launch_bounds__(256) void k_linear(const float* __restrict__ xin,
                                                const float* __restrict__ W,
                                                const float* __restrict__ a_src,
                                                const float* __restrict__ a_dst,
                                                float* __restrict__ hlin,
                                                float* __restrict__ asrc,
                                                float* __restrict__ adst, int ntot) {
  __shared__ __align__(16) float w_lds[32 * 128];
  __shared__ __align__(16) float x_lds[64 * 36];
  __shared__ float red_s[256];
  __shared__ float red_d[256];
  const int t = threadIdx.x;
  const int tx = t & 15, ty = t >> 4;
  const int n0 = blockIdx.x * 64;

  float acc[4][8];
#pragma unroll
  for (int r = 0; r < 4; r++)
#pragma unroll
    for (int j = 0; j < 8; j++) acc[r][j] = 0.f;

  for (int kc = 0; kc < 128; kc += 32) {
#pragma unroll
    for (int i = 0; i < 4; i++) {
      int idx = i * 256 + t;
      int kr = idx >> 5, c4 = idx & 31;
      ((float4*)w_lds)[kr * 32 + c4] = ((const float4*)W)[(kc + kr) * 32 + c4];
    }
#pragma unroll
    for (int i = 0; i < 2; i++) {
      int idx = i * 256 + t;
      int r = idx >> 3, k4 = idx & 7;
      int n = n0 + r;
      float4 v = make_float4(0.f, 0.f, 0.f, 0.f);
      if (n < ntot) v = ((const float4*)xin)[n * 32 + (kc >> 2) + k4];
      *((float4*)&x_lds[r * 36 + k4 * 4]) = v;
    }
    __syncthreads();
#pragma unroll
    for (int kk = 0; kk < 32; kk += 4) {
      float4 xv[4];
#pragma unroll
      for (int rr = 0; rr < 4; rr++)
        xv[rr] = *((const float4*)&x_lds[(ty * 4 + rr) * 36 + kk]);
#pragma unroll
      for (int q = 0; q < 4; q++) {
        int k = kk + q;
        float4 w0 = ((const float4*)w_lds)[k * 32 + tx];
        float4 w1 = ((const float4*)w_lds)[k * 32 + 16 + tx];
#pragma unroll
        for (int rr = 0; rr < 4; rr++) {
          float xs = q == 0 ? xv[rr].x : q == 1 ? xv[rr].y : q == 2 ? xv[rr].z : xv[rr].w;
          acc[rr][0] += xs * w0.x;
          acc[rr][1] += xs * w0.y;
          acc[rr][2] += xs * w0.z;
          acc[rr][3] += xs * w0.w;
          acc[rr][4] += xs * w1.x;
          acc[rr][5] += xs * w1.y;
          acc[rr][6] += xs * w1.z;
          acc[rr][7] += xs * w1.w;
        }
      }
    }
    __syncthreads();
  }

  red_s[t] = 0.f;
  red_d[t] = 0.f;
  __syncthreads();
  const int hA = tx >> 3, hB = 2 + (tx >> 3);
#pragma unroll
  for (int rr = 0; rr < 4; rr++) {
    int n = n0 + ty * 4 + rr;
    if (n < ntot) {
      float4 o0 = make_float4(acc[rr][0], acc[rr][1], acc[rr][2], acc[rr][3]);
      float4 o1 = make_float4(acc[rr][4], acc[rr][5], acc[rr][6], acc[rr][7]);
      ((float4*)hlin)[n * 32 + tx] = o0;
      ((float4*)hlin)[n * 32 + 16 + tx] = o1;
      float sA = 0.f, sB = 0.f, dA = 0.f, dB = 0.f;
#pragma unroll
      for (int j = 0; j < 4; j++) {
        sA += acc[rr][j] * a_src[tx * 4 + j];
        dA += acc[rr][j] * a_dst[tx * 4 + j];
        sB += acc[rr][4 + j] * a_src[64 + tx * 4 + j];
        dB += acc[rr][4 + j] * a_dst[64 + tx * 4 + j];
      }
      int r = ty * 4 + rr;
      atomicAdd(&red_s[r * 4 + hA], sA);
      atomicAdd(&red_s[r * 4 + hB], sB);
      atomicAdd(&red_d[r * 4 + hA], dA);
      atomicAdd(&red_d[r * 4 + hB], dB);
    }
  }
  __syncthreads();
  {
    int r = t >> 2, hd = t & 3;
    int n = n0 + r;
    if (n < ntot) {
      asrc[n * 4 + hd] = red_s[t];
      adst[n * 4 + hd] = red_d[t];
    }
  }
}

// ---------------- aggregate: one wave per destination node ----------------
__global__ __launch_bounds__(256) void k_aggregate(const float* __restrict__ hlin,
                                                   const float* __restrict__ asrcv,
                                                   const float* __restrict__ adstv,
                                                   const int* __restrict__ roff,
                                                   const int* __restrict__ ssrc,
                                                   const float* __restrict__ bias,
                                                   float* __restrict__ hout, int ntot) {
  const int lane = threadIdx.x & 63;
  const int n = blockIdx.x * 4 + (threadIdx.x >> 6);
  if (n >= ntot) return;
  const int beg = roff[n], end = roff[n + 1];
  const float4 ad = ((const float4*)adstv)[n];
  const float4 a_self = ((const float4*)asrcv)[n];

  float es0 = leaky(a_self.x + ad.x), es1 = leaky(a_self.y + ad.y);
  float es2 = leaky(a_self.z + ad.z), es3 = leaky(a_self.w + ad.w);
  float m0 = es0, m1 = es1, m2 = es2, m3 = es3;
  for (int i = beg + lane; i < end; i += 64) {
    int s = ssrc[i];
    float4 a = ((const float4*)asrcv)[s];
    m0 = fmaxf(m0, leaky(a.x + ad.x));
    m1 = fmaxf(m1, leaky(a.y + ad.y));
    m2 = fmaxf(m2, leaky(a.z + ad.z));
    m3 = fmaxf(m3, leaky(a.w + ad.w));
  }
#pragma unroll
  for (int off = 1; off < 64; off <<= 1) {
    m0 = fmaxf(m0, __shfl_xor(m0, off));
    m1 = fmaxf(m1, __shfl_xor(m1, off));
    m2 = fmaxf(m2, __shfl_xor(m2, off));
    m3 = fmaxf(m3, __shfl_xor(m3, off));
  }

  const int hh = lane >> 4;
  float2 hv = ((const float2*)hlin)[n * 64 + lane];
  float e0s = __expf(es0 - m0), e1s = __expf(es1 - m1);
  float e2s = __expf(es2 - m2), e3s = __expf(es3 - m3);
  float exsh = hh == 0 ? e0s : hh == 1 ? e1s : hh == 2 ? e2s : e3s;
  float acc0 = exsh * hv.x, acc1 = exsh * hv.y;
  float d0 = 0.f, d1 = 0.f, d2 = 0.f, d3 = 0.f;

  for (int base = beg; base < end; base += 64) {
    int myi = base + lane;
    int s = 0;
    float e0 = 0.f, e1 = 0.f, e2 = 0.f, e3 = 0.f;
    if (myi < end) {
      s = ssrc[myi];
      float4 a = ((const float4*)asrcv)[s];
      e0 = __expf(leaky(a.x + ad.x) - m0); d0 += e0;
      e1 = __expf(leaky(a.y + ad.y) - m1); d1 += e1;
      e2 = __expf(leaky(a.z + ad.z) - m2); d2 += e2;
      e3 = __expf(leaky(a.w + ad.w) - m3); d3 += e3;
    }
    int cnt = min(64, end - base);
    for (int j = 0; j < cnt; j++) {
      int sj = __shfl(s, j);
      float x0 = __shfl(e0, j), x1 = __shfl(e1, j);
      float x2 = __shfl(e2, j), x3 = __shfl(e3, j);
      float exj = hh == 0 ? x0 : hh == 1 ? x1 : hh == 2 ? x2 : x3;
      float2 hs = ((const float2*)hlin)[sj * 64 + lane];
      acc0 += exj * hs.x;
      acc1 += exj * hs.y;
    }
  }
#pragma unroll
  for (int off = 1; off < 64; off <<= 1) {
    d0 += __shfl_xor(d0, off);
    d1 += __shfl_xor(d1, off);
    d2 += __shfl_xor(d2, off);
    d3 += __shfl_xor(d3, off);
  }
  d0 += e0s; d1 += e1s; d2 += e2s; d3 += e3s;
  float dh = hh == 0 ? d0 : hh == 1 ? d1 : hh == 2 ? d2 : d3;
  float inv = 1.f / (dh + GEPS);
  int c0 = lane * 2;
  float o0 = fmaxf(acc0 * inv + bias[c0], 0.f);
  float o1 = fmaxf(acc1 * inv + bias[c0 + 1], 0.f);
  hout[n * DIM + c0] = o0;
  hout[n * DIM + c0 + 1] = o1;
}

// ---------------- global attention pooling ----------------
__global__ __launch_bounds__(256) void k_pool(const float* __restrict__ h,
                                              const float* __restrict__ gate_w,
                                              const float* __restrict__ gate_b,
                                              float* __restrict__ acc_out) {
  const int lane = threadIdx.x & 63;
  const int widg = blockIdx.x * 4 + (threadIdx.x >> 6);
  const int nw = gridDim.x * 4;
  const float w0 = gate_w[lane * 2], w1 = gate_w[lane * 2 + 1];
  const float gb = gate_b[0];
  float acc0 = 0.f, acc1 = 0.f, se = 0.f;
  for (int n = widg; n < NN; n += nw) {
    float2 hv = ((const float2*)h)[n * 64 + lane];
    float p = hv.x * w0 + hv.y * w1;
#pragma unroll
    for (int off = 1; off < 64; off <<= 1) p += __shfl_xor(p, off);
    float sg = 1.f / (1.f + __expf(-(p + gb)));
    float e = __expf(sg);
    se += e;
    acc0 += e * hv.x;
    acc1 += e * hv.y;
  }
  atomicAdd(&acc_out[lane * 2], acc0);
  atomicAdd(&acc_out[lane * 2 + 1], acc1);
  if (lane == 0) atomicAdd(&acc_out[128], se);
}

// ---------------- final MLP ----------------
__global__ __launch_bounds__(128) void k_mlp(const float* __restrict__ p1,
                                             const float* __restrict__ p2,
                                             const float* __restrict__ fc1_w,
                                             const float* __restrict__ fc1_b,
                                             const float* __restrict__ fc2_w,
                                             const float* __restrict__ fc2_b,
                                             float* __restrict__ out) {
  __shared__ float cat[256];
  __shared__ float red[2];
  const int t = threadIdx.x;
  cat[t] = p1[t] / p1[128];
  cat[128 + t] = p2[t] / p2[128];
  __syncthreads();
  float a = fc1_b[t];
  for (int k = 0; k < 256; k++) a += cat[k] * fc1_w[k * 128 + t];
  a = fmaxf(a, 0.f);
  float v = a * fc2_w[t];
#pragma unroll
  for (int off = 1; off < 64; off <<= 1) v += __shfl_xor(v, off);
  if ((t & 63) == 0) red[t >> 6] = v;
  __syncthreads();
  if (t == 0) out[0] = red[0] + red[1] + fc2_b[0];
}

extern "C" void kernel_launch(void* const* d_in, const int* in_sizes, int n_in,
                              void* d_out, int out_size, void* d_ws, size_t ws_size,
                              hipStream_t stream) {
  (void)in_sizes; (void)n_in; (void)out_size;
  const int* x1 = (const int*)d_in[0];
  const int* x2 = (const int*)d_in[1];
  const int* ei1 = (const int*)d_in[2];
  const int* ei2 = (const int*)d_in[3];
  const float* embed = (const float*)d_in[4];
  const float* W = (const float*)d_in[5];
  const float* attS = (const float*)d_in[6];
  const float* attD = (const float*)d_in[7];
  const float* bias = (const float*)d_in[8];
  const float* gw = (const float*)d_in[9];
  const float* gb = (const float*)d_in[10];
  const float* f1w = (const float*)d_in[11];
  const float* f1b = (const float*)d_in[12];
  const float* f2w = (const float*)d_in[13];
  const float* f2b = (const float*)d_in[14];
  float* out = (float*)d_out;

  // combined (2-graph) workspace requirement
  auto req = [](int nt, int net) {
    size_t s = 0;
    auto pad = [&](size_t b) { s = (s + b + 255) & ~size_t(255); };
    pad(size_t(nt) * DIM * 4);      // h_in
    pad(size_t(nt) * DIM * 4);      // h_lin
    pad(size_t(nt) * 16);           // asrc
    pad(size_t(nt) * 16);           // adst
    pad(size_t(nt + 1) * 4);        // roff
    pad(size_t(nt) * 4);            // cur
    pad(size_t(net) * 4);           // ssrc
    pad(128 * 4);                   // partials
    pad(2 * 129 * 4);               // pool
    return s;
  };
  const bool combined = ws_size >= req(2 * NN, 2 * NE);
  const int nt = combined ? 2 * NN : NN;
  const int net = combined ? 2 * NE : NE;

  char* ws = (char*)d_ws;
  size_t off = 0;
  auto alloc = [&](size_t bytes) {
    void* p = ws + off;
    off = (off + bytes + 255) & ~size_t(255);
    return p;
  };
  float* h_in = (float*)alloc(size_t(nt) * DIM * 4);
  float* h_lin = (float*)alloc(size_t(nt) * DIM * 4);
  float* asrc = (float*)alloc(size_t(nt) * 16);
  float* adst = (float*)alloc(size_t(nt) * 16);
  int* roff = (int*)alloc(size_t(nt + 1) * 4);
  int* cur = (int*)alloc(size_t(nt) * 4);
  int* ssrc = (int*)alloc(size_t(net) * 4);
  int* partials = (int*)alloc(128 * 4);
  float* pool = (float*)alloc(2 * 129 * 4);

  hipMemsetAsync(pool, 0, 2 * 129 * 4, stream);

  const int nb = (nt + 1023) / 1024;

  auto run_graphs = [&](const int* xA, const int* xB, const int* eA, const int* eB) {
    k_gather<<<(nt * 32 + 255) / 256, 256, 0, stream>>>(xA, xB, embed, h_in, nt);
    hipMemsetAsync(cur, 0, size_t(nt) * 4, stream);
    k_count<<<(net + 255) / 256, 256, 0, stream>>>(eA + NE, eB + NE, cur, net);
    k_scan1<<<nb, 1024, 0, stream>>>(cur, roff, partials, nt);
    k_scan2<<<1, 128, 0, stream>>>(partials, nb);
    k_scan3<<<nb, 1024, 0, stream>>>(roff, cur, partials, nt, net);
    k_fill<<<(net + 255) / 256, 256, 0, stream>>>(eA, eA + NE, eB, eB + NE, cur, ssrc, net);
    for (int l = 0; l < 3; ++l) {
      k_linear<<<(nt + 63) / 64, 256, 0, stream>>>(
          h_in, W + l * DIM * DIM, attS + l * DIM, attD + l * DIM, h_lin, asrc, adst, nt);
      k_aggregate<<<(nt + 3) / 4, 256, 0, stream>>>(
          h_lin, asrc, adst, roff, ssrc, bias + l * DIM, h_in, nt);
    }
  };

  if (combined) {
    run_graphs(x1, x2, ei1, ei2);
    k_pool<<<128, 256, 0, stream>>>(h_in, gw, gb, pool);
    k_pool<<<128, 256, 0, stream>>>(h_in + size_t(NN) * DIM, gw, gb, pool + 129);
  } else {
    run_graphs(x1, x1, ei1, ei1);
    k_pool<<<128, 256, 0, stream>>>(h_in, gw, gb, pool);
    run_graphs(x2, x2, ei2, ei2);
    k_pool<<<128, 256, 0, stream>>>(h_in, gw, gb, pool + 129);
  }
  k_mlp<<<1, 128, 0, stream>>>(pool, pool + 129, f1w, f1b, f2w, f2b, out);
}

// Round 3
// 870.529 us; speedup vs baseline: 1.4611x; 1.1059x over previous
//
#include <hip/hip_runtime.h>
#include <hip/hip_bf16.h>

#define NN 50000
#define NE 600000
#define DIM 128
#define NEG 0.2f
#define GEPS 1e-16f

__device__ __forceinline__ float leaky(float x) { return x > 0.f ? x : NEG * x; }

// ---------------- embed gather: h[n][:] = embed[idx(n)][:] ----------------
__global__ __launch_bounds__(256) void k_gather(const int* __restrict__ xA,
                                                const int* __restrict__ xB,
                                                const float* __restrict__ embed,
                                                float* __restrict__ h, int ntot) {
  int i = blockIdx.x * blockDim.x + threadIdx.x;  // over ntot*32 float4s
  if (i >= ntot * 32) return;
  int n = i >> 5, c4 = i & 31;
  int v = (n < NN) ? xA[n] : xB[n - NN];
  ((float4*)h)[n * 32 + c4] = ((const float4*)embed)[v * 32 + c4];
}

// ---------------- CSR build ----------------
__global__ __launch_bounds__(256) void k_count(const int* __restrict__ d1,
                                               const int* __restrict__ d2,
                                               int* __restrict__ cnt, int netot) {
  int e = blockIdx.x * blockDim.x + threadIdx.x;
  if (e >= netot) return;
  int dst = (e < NE) ? d1[e] : d2[e - NE] + NN;
  atomicAdd(&cnt[dst], 1);
}

__global__ __launch_bounds__(1024) void k_scan1(const int* __restrict__ cnt,
                                                int* __restrict__ roff,
                                                int* __restrict__ partials, int nn) {
  __shared__ int part[1024];
  const int t = threadIdx.x;
  const int idx = blockIdx.x * 1024 + t;
  int v = (idx < nn) ? cnt[idx] : 0;
  part[t] = v;
  __syncthreads();
  for (int off = 1; off < 1024; off <<= 1) {
    int x = (t >= off) ? part[t - off] : 0;
    __syncthreads();
    part[t] += x;
    __syncthreads();
  }
  if (idx < nn) roff[idx] = part[t] - v;
  if (t == 1023) partials[blockIdx.x] = part[1023];
}

__global__ __launch_bounds__(128) void k_scan2(int* __restrict__ partials, int nb) {
  __shared__ int part[128];
  const int t = threadIdx.x;
  int v = (t < nb) ? partials[t] : 0;
  part[t] = v;
  __syncthreads();
  for (int off = 1; off < 128; off <<= 1) {
    int x = (t >= off) ? part[t - off] : 0;
    __syncthreads();
    part[t] += x;
    __syncthreads();
  }
  if (t < nb) partials[t] = part[t] - v;
}

__global__ __launch_bounds__(1024) void k_scan3(int* __restrict__ roff,
                                                int* __restrict__ cur,
                                                const int* __restrict__ partials,
                                                int nn, int netot) {
  int idx = blockIdx.x * 1024 + threadIdx.x;
  if (idx < nn) {
    int v = roff[idx] + partials[blockIdx.x];
    roff[idx] = v;
    cur[idx] = v;
  }
  if (idx == 0) roff[nn] = netot;
}

__global__ __launch_bounds__(256) void k_fill(const int* __restrict__ s1,
                                              const int* __restrict__ d1,
                                              const int* __restrict__ s2,
                                              const int* __restrict__ d2,
                                              int* __restrict__ cur,
                                              int* __restrict__ ssrc, int netot) {
  int e = blockIdx.x * blockDim.x + threadIdx.x;
  if (e >= netot) return;
  int s, d;
  if (e < NE) { s = s1[e]; d = d1[e]; }
  else        { s = s2[e - NE] + NN; d = d2[e - NE] + NN; }
  int p = atomicAdd(&cur[d], 1);
  ssrc[p] = s;
}

// ---------------- linear: hlin = xin @ W, + attention dot products ----------------
__global__ __launch_bounds__(256) void k_linear(const float* __restrict__ xin,
                                                const float* __restrict__ W,
                                                const float* __restrict__ a_src,
                                                const float* __restrict__ a_dst,
                                                float* __restrict__ hlin,
                                                float* __restrict__ asrc,
                                                float* __restrict__ adst, int ntot) {
  __shared__ __align__(16) float w_lds[32 * 128];
  __shared__ __align__(16) float x_lds[64 * 36];
  __shared__ float red_s[256];
  __shared__ float red_d[256];
  const int t = threadIdx.x;
  const int tx = t & 15, ty = t >> 4;
  const int n0 = blockIdx.x * 64;

  float acc[4][8];
#pragma unroll
  for (int r = 0; r < 4; r++)
#pragma unroll
    for (int j = 0; j < 8; j++) acc[r][j] = 0.f;

  for (int kc = 0; kc < 128; kc += 32) {
#pragma unroll
    for (int i = 0; i < 4; i++) {
      int idx = i * 256 + t;
      int kr = idx >> 5, c4 = idx & 31;
      ((float4*)w_lds)[kr * 32 + c4] = ((const float4*)W)[(kc + kr) * 32 + c4];
    }
#pragma unroll
    for (int i = 0; i < 2; i++) {
      int idx = i * 256 + t;
      int r = idx >> 3, k4 = idx & 7;
      int n = n0 + r;
      float4 v = make_float4(0.f, 0.f, 0.f, 0.f);
      if (n < ntot) v = ((const float4*)xin)[n * 32 + (kc >> 2) + k4];
      *((float4*)&x_lds[r * 36 + k4 * 4]) = v;
    }
    __syncthreads();
#pragma unroll
    for (int kk = 0; kk < 32; kk += 4) {
      float4 xv[4];
#pragma unroll
      for (int rr = 0; rr < 4; rr++)
        xv[rr] = *((const float4*)&x_lds[(ty * 4 + rr) * 36 + kk]);
#pragma unroll
      for (int q = 0; q < 4; q++) {
        int k = kk + q;
        float4 w0 = ((const float4*)w_lds)[k * 32 + tx];
        float4 w1 = ((const float4*)w_lds)[k * 32 + 16 + tx];
#pragma unroll
        for (int rr = 0; rr < 4; rr++) {
          float xs = q == 0 ? xv[rr].x : q == 1 ? xv[rr].y : q == 2 ? xv[rr].z : xv[rr].w;
          acc[rr][0] += xs * w0.x;
          acc[rr][1] += xs * w0.y;
          acc[rr][2] += xs * w0.z;
          acc[rr][3] += xs * w0.w;
          acc[rr][4] += xs * w1.x;
          acc[rr][5] += xs * w1.y;
          acc[rr][6] += xs * w1.z;
          acc[rr][7] += xs * w1.w;
        }
      }
    }
    __syncthreads();
  }

  red_s[t] = 0.f;
  red_d[t] = 0.f;
  __syncthreads();
  const int hA = tx >> 3, hB = 2 + (tx >> 3);
#pragma unroll
  for (int rr = 0; rr < 4; rr++) {
    int n = n0 + ty * 4 + rr;
    if (n < ntot) {
      float4 o0 = make_float4(acc[rr][0], acc[rr][1], acc[rr][2], acc[rr][3]);
      float4 o1 = make_float4(acc[rr][4], acc[rr][5], acc[rr][6], acc[rr][7]);
      ((float4*)hlin)[n * 32 + tx] = o0;
      ((float4*)hlin)[n * 32 + 16 + tx] = o1;
      float sA = 0.f, sB = 0.f, dA = 0.f, dB = 0.f;
#pragma unroll
      for (int j = 0; j < 4; j++) {
        sA += acc[rr][j] * a_src[tx * 4 + j];
        dA += acc[rr][j] * a_dst[tx * 4 + j];
        sB += acc[rr][4 + j] * a_src[64 + tx * 4 + j];
        dB += acc[rr][4 + j] * a_dst[64 + tx * 4 + j];
      }
      int r = ty * 4 + rr;
      atomicAdd(&red_s[r * 4 + hA], sA);
      atomicAdd(&red_s[r * 4 + hB], sB);
      atomicAdd(&red_d[r * 4 + hA], dA);
      atomicAdd(&red_d[r * 4 + hB], dB);
    }
  }
  __syncthreads();
  {
    int r = t >> 2, hd = t & 3;
    int n = n0 + r;
    if (n < ntot) {
      asrc[n * 4 + hd] = red_s[t];
      adst[n * 4 + hd] = red_d[t];
    }
  }
}

// ---------------- aggregate: one wave per destination node ----------------
// lane k = (head hh = k>>4, edge-slot sub = k&15); softmax without max-sub
// (exp(e)/sum(exp(e)) == exp(e-m)/sum(exp(e-m)), e bounded so no overflow);
// denom accumulated inside the PV loop (no butterfly reductions at all).
__global__ __launch_bounds__(256) void k_aggregate(const float* __restrict__ hlin,
                                                   const float* __restrict__ asrcv,
                                                   const float* __restrict__ adstv,
                                                   const int* __restrict__ roff,
                                                   const int* __restrict__ ssrc,
                                                   const float* __restrict__ bias,
                                                   float* __restrict__ hout, int ntot) {
  const int lane = threadIdx.x & 63;
  const int n = blockIdx.x * 4 + (threadIdx.x >> 6);
  if (n >= ntot) return;
  const int hh = lane >> 4;   // head of this lane's columns
  const int sub = lane & 15;  // edge slot within 16-edge chunk
  const int beg = roff[n], end = roff[n + 1];
  const int deg = end - beg;

  const float adh = adstv[n * 4 + hh];
  const float ash = asrcv[n * 4 + hh];
  const float pself = __expf(leaky(ash + adh));

  const int c0 = lane * 2;
  float2 hv = ((const float2*)hlin)[n * 64 + lane];
  float acc0 = pself * hv.x, acc1 = pself * hv.y;
  float dh = pself;

  for (int base = 0; base < deg; base += 16) {
    int cnt = deg - base; if (cnt > 16) cnt = 16;
    int s = 0;
    float px = 0.f;
    if (sub < cnt) {
      s = ssrc[beg + base + sub];
      float as = asrcv[s * 4 + hh];
      px = __expf(leaky(as + adh));
    }
    // fully-unrolled predicated broadcast loop: 2 bpermutes/edge, 16
    // independent gathers in flight
#pragma unroll
    for (int j = 0; j < 16; j++) {
      int srcl = (lane & 48) + j;
      int sj = __shfl(s, srcl);
      float exj = __shfl(px, srcl);
      float2 hs = ((const float2*)hlin)[sj * 64 + lane];
      acc0 += exj * hs.x;
      acc1 += exj * hs.y;
      dh += exj;
    }
  }
  float inv = 1.f / (dh + GEPS);
  float o0 = fmaxf(acc0 * inv + bias[c0], 0.f);
  float o1 = fmaxf(acc1 * inv + bias[c0 + 1], 0.f);
  hout[n * DIM + c0] = o0;
  hout[n * DIM + c0 + 1] = o1;
}

// ---------------- global attention pooling ----------------
__global__ __launch_bounds__(256) void k_pool(const float* __restrict__ h,
                                              const float* __restrict__ gate_w,
                                              const float* __restrict__ gate_b,
                                              float* __restrict__ acc_out) {
  const int lane = threadIdx.x & 63;
  const int widg = blockIdx.x * 4 + (threadIdx.x >> 6);
  const int nw = gridDim.x * 4;
  const float w0 = gate_w[lane * 2], w1 = gate_w[lane * 2 + 1];
  const float gb = gate_b[0];
  float acc0 = 0.f, acc1 = 0.f, se = 0.f;
  for (int n = widg; n < NN; n += nw) {
    float2 hv = ((const float2*)h)[n * 64 + lane];
    float p = hv.x * w0 + hv.y * w1;
#pragma unroll
    for (int off = 1; off < 64; off <<= 1) p += __shfl_xor(p, off);
    float sg = 1.f / (1.f + __expf(-(p + gb)));
    float e = __expf(sg);
    se += e;
    acc0 += e * hv.x;
    acc1 += e * hv.y;
  }
  atomicAdd(&acc_out[lane * 2], acc0);
  atomicAdd(&acc_out[lane * 2 + 1], acc1);
  if (lane == 0) atomicAdd(&acc_out[128], se);
}

// ---------------- final MLP ----------------
__global__ __launch_bounds__(128) void k_mlp(const float* __restrict__ p1,
                                             const float* __restrict__ p2,
                                             const float* __restrict__ fc1_w,
                                             const float* __restrict__ fc1_b,
                                             const float* __restrict__ fc2_w,
                                             const float* __restrict__ fc2_b,
                                             float* __restrict__ out) {
  __shared__ float cat[256];
  __shared__ float red[2];
  const int t = threadIdx.x;
  cat[t] = p1[t] / p1[128];
  cat[128 + t] = p2[t] / p2[128];
  __syncthreads();
  float a = fc1_b[t];
  for (int k = 0; k < 256; k++) a += cat[k] * fc1_w[k * 128 + t];
  a = fmaxf(a, 0.f);
  float v = a * fc2_w[t];
#pragma unroll
  for (int off = 1; off < 64; off <<= 1) v += __shfl_xor(v, off);
  if ((t & 63) == 0) red[t >> 6] = v;
  __syncthreads();
  if (t == 0) out[0] = red[0] + red[1] + fc2_b[0];
}

extern "C" void kernel_launch(void* const* d_in, const int* in_sizes, int n_in,
                              void* d_out, int out_size, void* d_ws, size_t ws_size,
                              hipStream_t stream) {
  (void)in_sizes; (void)n_in; (void)out_size;
  const int* x1 = (const int*)d_in[0];
  const int* x2 = (const int*)d_in[1];
  const int* ei1 = (const int*)d_in[2];
  const int* ei2 = (const int*)d_in[3];
  const float* embed = (const float*)d_in[4];
  const float* W = (const float*)d_in[5];
  const float* attS = (const float*)d_in[6];
  const float* attD = (const float*)d_in[7];
  const float* bias = (const float*)d_in[8];
  const float* gw = (const float*)d_in[9];
  const float* gb = (const float*)d_in[10];
  const float* f1w = (const float*)d_in[11];
  const float* f1b = (const float*)d_in[12];
  const float* f2w = (const float*)d_in[13];
  const float* f2b = (const float*)d_in[14];
  float* out = (float*)d_out;

  auto req = [](int nt, int net) {
    size_t s = 0;
    auto pad = [&](size_t b) { s = (s + b + 255) & ~size_t(255); };
    pad(size_t(nt) * DIM * 4);
    pad(size_t(nt) * DIM * 4);
    pad(size_t(nt) * 16);
    pad(size_t(nt) * 16);
    pad(size_t(nt + 1) * 4);
    pad(size_t(nt) * 4);
    pad(size_t(net) * 4);
    pad(128 * 4);
    pad(2 * 129 * 4);
    return s;
  };
  const bool combined = ws_size >= req(2 * NN, 2 * NE);
  const int nt = combined ? 2 * NN : NN;
  const int net = combined ? 2 * NE : NE;

  char* ws = (char*)d_ws;
  size_t off = 0;
  auto alloc = [&](size_t bytes) {
    void* p = ws + off;
    off = (off + bytes + 255) & ~size_t(255);
    return p;
  };
  float* h_in = (float*)alloc(size_t(nt) * DIM * 4);
  float* h_lin = (float*)alloc(size_t(nt) * DIM * 4);
  float* asrc = (float*)alloc(size_t(nt) * 16);
  float* adst = (float*)alloc(size_t(nt) * 16);
  int* roff = (int*)alloc(size_t(nt + 1) * 4);
  int* cur = (int*)alloc(size_t(nt) * 4);
  int* ssrc = (int*)alloc(size_t(net) * 4);
  int* partials = (int*)alloc(128 * 4);
  float* pool = (float*)alloc(2 * 129 * 4);

  hipMemsetAsync(pool, 0, 2 * 129 * 4, stream);

  const int nb = (nt + 1023) / 1024;

  auto run_graphs = [&](const int* xA, const int* xB, const int* eA, const int* eB) {
    k_gather<<<(nt * 32 + 255) / 256, 256, 0, stream>>>(xA, xB, embed, h_in, nt);
    hipMemsetAsync(cur, 0, size_t(nt) * 4, stream);
    k_count<<<(net + 255) / 256, 256, 0, stream>>>(eA + NE, eB + NE, cur, net);
    k_scan1<<<nb, 1024, 0, stream>>>(cur, roff, partials, nt);
    k_scan2<<<1, 128, 0, stream>>>(partials, nb);
    k_scan3<<<nb, 1024, 0, stream>>>(roff, cur, partials, nt, net);
    k_fill<<<(net + 255) / 256, 256, 0, stream>>>(eA, eA + NE, eB, eB + NE, cur, ssrc, net);
    for (int l = 0; l < 3; ++l) {
      k_linear<<<(nt + 63) / 64, 256, 0, stream>>>(
          h_in, W + l * DIM * DIM, attS + l * DIM, attD + l * DIM, h_lin, asrc, adst, nt);
      k_aggregate<<<(nt + 3) / 4, 256, 0, stream>>>(
          h_lin, asrc, adst, roff, ssrc, bias + l * DIM, h_in, nt);
    }
  };

  if (combined) {
    run_graphs(x1, x2, ei1, ei2);
    k_pool<<<128, 256, 0, stream>>>(h_in, gw, gb, pool);
    k_pool<<<128, 256, 0, stream>>>(h_in + size_t(NN) * DIM, gw, gb, pool + 129);
  } else {
    run_graphs(x1, x1, ei1, ei1);
    k_pool<<<128, 256, 0, stream>>>(h_in, gw, gb, pool);
    run_graphs(x2, x2, ei2, ei2);
    k_pool<<<128, 256, 0, stream>>>(h_in, gw, gb, pool + 129);
  }
  k_mlp<<<1, 128, 0, stream>>>(pool, pool + 129, f1w, f1b, f2w, f2b, out);
}